// Round 1
// baseline (136.452 us; speedup 1.0000x reference)
//
#include <hip/hip_runtime.h>
#include <math.h>

// Problem shape (fixed by harness reference)
#define B_SZ 32
#define N_SZ 2048
#define M_SZ 2048
#define D_SZ 32

// Tiling
#define BN 128
#define BM 128
#define PAD 4
#define LDSROW (BN + PAD)   // 132 floats; keeps 16B alignment for float4 reads

__global__ __launch_bounds__(256)
void sqnorm_kernel(const float* __restrict__ P, float* __restrict__ out, int total_rows) {
    int r = blockIdx.x * blockDim.x + threadIdx.x;
    if (r >= total_rows) return;
    const float4* p = reinterpret_cast<const float4*>(P) + (size_t)r * (D_SZ / 4);
    float s = 0.f;
#pragma unroll
    for (int i = 0; i < D_SZ / 4; ++i) {
        float4 v = p[i];
        s = fmaf(v.x, v.x, s); s = fmaf(v.y, v.y, s);
        s = fmaf(v.z, v.z, s); s = fmaf(v.w, v.w, s);
    }
    out[r] = s;
}

__global__ __launch_bounds__(256)
void chamfer_main(const float* __restrict__ X, const float* __restrict__ Y,
                  const float* __restrict__ x2g, const float* __restrict__ y2g,
                  float* __restrict__ rowmin_g, unsigned int* __restrict__ colmin_g) {
    __shared__ float Xs[D_SZ][LDSROW];
    __shared__ float Ys[D_SZ][LDSROW];
    __shared__ float red[16][LDSROW];

    const int tid = threadIdx.x;
    const int ti = tid >> 4;   // 0..15 (n-group)
    const int tj = tid & 15;   // 0..15 (m-group)
    const int b  = blockIdx.y;
    const int n0 = blockIdx.x * BN;

    const float* Xb = X + ((size_t)b * N_SZ + n0) * D_SZ;
    const float* Yb = Y + (size_t)b * M_SZ * D_SZ;

    // ---- stage X tile, transposed: Xs[d][n_local] ----
    {
        const float4* src = reinterpret_cast<const float4*>(Xb);
#pragma unroll
        for (int r = 0; r < 4; ++r) {
            int f = tid + 256 * r;      // 0..1023 float4s, fully coalesced
            int row = f >> 3;           // 0..127
            int q = f & 7;              // which float4 in the row
            float4 v = src[f];
            Xs[4*q+0][row] = v.x;
            Xs[4*q+1][row] = v.y;
            Xs[4*q+2][row] = v.z;
            Xs[4*q+3][row] = v.w;
        }
    }

    float x2i[8], rmin[8];
#pragma unroll
    for (int i = 0; i < 8; ++i) {
        x2i[i] = x2g[(size_t)b * N_SZ + n0 + ti * 8 + i];
        rmin[i] = 3.0e38f;
    }

    for (int m0 = 0; m0 < M_SZ; m0 += BM) {
        __syncthreads();   // protect Ys + red from previous iteration readers
        // ---- stage Y tile, transposed ----
        {
            const float4* src = reinterpret_cast<const float4*>(Yb + (size_t)m0 * D_SZ);
#pragma unroll
            for (int r = 0; r < 4; ++r) {
                int f = tid + 256 * r;
                int row = f >> 3;
                int q = f & 7;
                float4 v = src[f];
                Ys[4*q+0][row] = v.x;
                Ys[4*q+1][row] = v.y;
                Ys[4*q+2][row] = v.z;
                Ys[4*q+3][row] = v.w;
            }
        }
        float y2j[8];
#pragma unroll
        for (int j = 0; j < 8; ++j)
            y2j[j] = y2g[(size_t)b * M_SZ + m0 + tj * 8 + j];
        __syncthreads();

        float acc[8][8];
#pragma unroll
        for (int i = 0; i < 8; ++i)
#pragma unroll
            for (int j = 0; j < 8; ++j) acc[i][j] = 0.f;

#pragma unroll 4
        for (int d = 0; d < D_SZ; ++d) {
            const float4* xp = reinterpret_cast<const float4*>(&Xs[d][ti * 8]);
            const float4* yp = reinterpret_cast<const float4*>(&Ys[d][tj * 8]);
            float4 xa = xp[0], xb4 = xp[1];
            float4 ya = yp[0], yb4 = yp[1];
            float xf[8] = {xa.x, xa.y, xa.z, xa.w, xb4.x, xb4.y, xb4.z, xb4.w};
            float yf[8] = {ya.x, ya.y, ya.z, ya.w, yb4.x, yb4.y, yb4.z, yb4.w};
#pragma unroll
            for (int i = 0; i < 8; ++i)
#pragma unroll
                for (int j = 0; j < 8; ++j)
                    acc[i][j] = fmaf(xf[i], yf[j], acc[i][j]);
        }

        // ---- epilogue: d2 = x2 + y2 - 2*dot, clamp >= 0, update mins ----
        float cmin[8];
#pragma unroll
        for (int j = 0; j < 8; ++j) cmin[j] = 3.0e38f;
#pragma unroll
        for (int i = 0; i < 8; ++i) {
#pragma unroll
            for (int j = 0; j < 8; ++j) {
                float d2 = fmaxf(fmaf(-2.f, acc[i][j], x2i[i] + y2j[j]), 0.f);
                rmin[i] = fminf(rmin[i], d2);
                cmin[j] = fminf(cmin[j], d2);
            }
        }

        // ---- column-min reduction across ti, then device atomicMin ----
#pragma unroll
        for (int j = 0; j < 8; ++j) red[ti][tj * 8 + j] = cmin[j];
        __syncthreads();
        if (tid < BM) {
            float v = red[0][tid];
#pragma unroll
            for (int t = 1; t < 16; ++t) v = fminf(v, red[t][tid]);
            // v >= 0, so uint bit pattern ordering == float ordering
            atomicMin(&colmin_g[(size_t)b * M_SZ + m0 + tid], __float_as_uint(v));
        }
    }

    // ---- row-min reduction across tj; exclusive ownership -> plain store ----
    __syncthreads();
#pragma unroll
    for (int i = 0; i < 8; ++i) red[tj][ti * 8 + i] = rmin[i];
    __syncthreads();
    if (tid < BN) {
        float v = red[0][tid];
#pragma unroll
        for (int t = 1; t < 16; ++t) v = fminf(v, red[t][tid]);
        rowmin_g[(size_t)b * N_SZ + n0 + tid] = v;
    }
}

__global__ __launch_bounds__(256)
void finalize1(const float* __restrict__ vals, float* __restrict__ partials, int total4) {
    const float4* v4 = reinterpret_cast<const float4*>(vals);
    float s = 0.f;
    for (int i = blockIdx.x * blockDim.x + threadIdx.x; i < total4;
         i += gridDim.x * blockDim.x) {
        float4 v = v4[i];
        s += sqrtf(fmaxf(v.x, 0.f)) + sqrtf(fmaxf(v.y, 0.f)) +
             sqrtf(fmaxf(v.z, 0.f)) + sqrtf(fmaxf(v.w, 0.f));
    }
    // block reduce (deterministic shuffle tree)
    __shared__ float wsum[4];
#pragma unroll
    for (int o = 32; o > 0; o >>= 1) s += __shfl_down(s, o, 64);
    if ((threadIdx.x & 63) == 0) wsum[threadIdx.x >> 6] = s;
    __syncthreads();
    if (threadIdx.x == 0) {
        float t = wsum[0] + wsum[1] + wsum[2] + wsum[3];
        partials[blockIdx.x] = t;
    }
}

__global__ __launch_bounds__(64)
void finalize2(const float* __restrict__ partials, float* __restrict__ out,
               float scale) {
    float s = partials[threadIdx.x];
#pragma unroll
    for (int o = 32; o > 0; o >>= 1) s += __shfl_down(s, o, 64);
    if (threadIdx.x == 0) out[0] = s * scale;
}

extern "C" void kernel_launch(void* const* d_in, const int* in_sizes, int n_in,
                              void* d_out, int out_size, void* d_ws, size_t ws_size,
                              hipStream_t stream) {
    const float* X = (const float*)d_in[0];
    const float* Y = (const float*)d_in[1];

    float* ws = (float*)d_ws;
    float* rowmin   = ws;                                   // B*N floats
    float* colmin   = ws + (size_t)B_SZ * N_SZ;             // B*M floats (contiguous with rowmin)
    float* partials = colmin + (size_t)B_SZ * M_SZ;         // 64 floats
    float* x2       = partials + 64;                        // B*N floats
    float* y2       = x2 + (size_t)B_SZ * N_SZ;             // B*M floats

    const int rowsX = B_SZ * N_SZ;
    const int rowsY = B_SZ * M_SZ;

    sqnorm_kernel<<<(rowsX + 255) / 256, 256, 0, stream>>>(X, x2, rowsX);
    sqnorm_kernel<<<(rowsY + 255) / 256, 256, 0, stream>>>(Y, y2, rowsY);

    // init colmin to large float (0x7F7F7F7F ~ 3.39e38); graph-capture safe
    hipMemsetAsync(colmin, 0x7F, (size_t)B_SZ * M_SZ * sizeof(float), stream);

    dim3 grid(N_SZ / BN, B_SZ);
    chamfer_main<<<grid, 256, 0, stream>>>(X, Y, x2, y2, rowmin,
                                           (unsigned int*)colmin);

    // rowmin and colmin are contiguous: sum sqrt over both in one pass
    finalize1<<<64, 256, 0, stream>>>(rowmin, partials, (2 * B_SZ * N_SZ) / 4);
    finalize2<<<1, 64, 0, stream>>>(partials, (float*)d_out,
                                    1.0f / (2.0f * B_SZ * N_SZ));
}

// Round 2
// 85.912 us; speedup vs baseline: 1.5883x; 1.5883x over previous
//
#include <hip/hip_runtime.h>
#include <math.h>

// Problem shape (fixed by harness reference)
#define B_SZ 32
#define N_SZ 2048
#define M_SZ 2048
#define D_SZ 32

typedef __attribute__((ext_vector_type(8))) _Float16 h8;   // MFMA A/B frag: 8 f16 = 4 VGPRs
typedef __attribute__((ext_vector_type(4))) float f4;      // MFMA C/D frag

// ---------------------------------------------------------------------------
// Pack X (and Y) into MFMA-fragment-ready f16 layout + fused squared norms.
// Tile t = 16 consecutive rows of the flattened [B*N] row space (2048%16==0,
// so tiles never straddle batches). Lane l of tile t holds:
//   row = t*16 + (l&15),  k = {4g+j} U {16+4g+j},  g = l>>4, j = 0..3
// (mfma_f32_16x16x32 = two stacked 16x16x16 K-halves; per-half k = 4g+j,
//  consistent with the measured ds_read_b64_tr_b16 layout, learn_hip m162.)
// Norms: lanes (l, l^16, l^32, l^48) hold disjoint k of the same row ->
// shfl_xor(16)+shfl_xor(32) sums the full row.
// ---------------------------------------------------------------------------
__global__ __launch_bounds__(256)
void pack_kernel(const float* __restrict__ srcX, const float* __restrict__ srcY,
                 h8* __restrict__ dstX, h8* __restrict__ dstY,
                 float* __restrict__ nrmX, float* __restrict__ nrmY)
{
    const int gid = blockIdx.x * 256 + threadIdx.x;   // one thread per (tile,lane)
    const float* src = blockIdx.y ? srcY : srcX;
    h8*          dst = blockIdx.y ? dstY : dstX;
    float*       nrm = blockIdx.y ? nrmY : nrmX;

    const int l   = gid & 63;
    const int t   = gid >> 6;
    const int row = t * 16 + (l & 15);
    const int k0  = (l >> 4) * 4;

    const float* p = src + (size_t)row * D_SZ;
    f4 v0 = *(const f4*)(p + k0);        // k = k0..k0+3
    f4 v1 = *(const f4*)(p + 16 + k0);   // k = 16+k0..16+k0+3

    h8 h;
    h[0] = (_Float16)v0[0]; h[1] = (_Float16)v0[1];
    h[2] = (_Float16)v0[2]; h[3] = (_Float16)v0[3];
    h[4] = (_Float16)v1[0]; h[5] = (_Float16)v1[1];
    h[6] = (_Float16)v1[2]; h[7] = (_Float16)v1[3];
    dst[gid] = h;

    float s = 0.f;
#pragma unroll
    for (int j = 0; j < 4; ++j) {
        s = fmaf(v0[j], v0[j], s);
        s = fmaf(v1[j], v1[j], s);
    }
    s += __shfl_xor(s, 16);
    s += __shfl_xor(s, 32);
    if (l < 16) nrm[row] = s;   // exact fp32 norms
}

// ---------------------------------------------------------------------------
// Main kernel: zero LDS, zero barriers. Block = 4 waves; wave owns 32 rows
// (2 A-frags held in registers). Loop over all 128 Y m-tiles: 1 coalesced
// 16B/lane B-frag load (L2-resident: packed Y = 4.2MB total) + 2 MFMAs +
// register epilogue. d2 = x2 + y2 - 2*dot (no clamp needed in-loop: min
// pairwise d2 of this data ~10, and finalize clamps before sqrt anyway).
// C/D layout (m89-verified): col = lane&15, row = (lane>>4)*4 + reg.
//  - rowmin: per-lane running min, shfl_xor{1,2,4,8} across cols at the end,
//    exclusive float4 store.
//  - colmin: per-tile min over the wave's 32 rows via shfl_xor{16,32}, then
//    one idempotent uint atomicMin (d2 >= 0 -> bit order == float order).
// ---------------------------------------------------------------------------
__global__ __launch_bounds__(256)
void chamfer_mfma(const h8* __restrict__ Xpk, const h8* __restrict__ Ypk,
                  const float* __restrict__ x2g, const float* __restrict__ y2g,
                  float* __restrict__ rowmin_g, unsigned int* __restrict__ colmin_g)
{
    const int tid = threadIdx.x;
    const int w   = tid >> 6;
    const int l   = tid & 63;
    const int lc  = l & 15;
    const int b   = blockIdx.y;
    const int row0 = blockIdx.x * 128 + w * 32;           // within batch
    const size_t tile0 = ((size_t)b * N_SZ + row0) >> 4;  // global 16-row tile

    // A fragments (2 subtiles of 16 rows) + exact fp32 row norms
    h8 a0 = Xpk[tile0 * 64 + l];
    h8 a1 = Xpk[(tile0 + 1) * 64 + l];
    f4 x20 = *(const f4*)(x2g + b * N_SZ + row0 + ((l >> 4) << 2));
    f4 x21 = *(const f4*)(x2g + b * N_SZ + row0 + 16 + ((l >> 4) << 2));

    const float INF = 3.0e38f;
    f4 rm0 = {INF, INF, INF, INF};
    f4 rm1 = {INF, INF, INF, INF};

    const h8*    yb  = Ypk + (size_t)b * (M_SZ / 16) * 64;
    const float* y2b = y2g + (size_t)b * M_SZ;
    unsigned int* cmb = colmin_g + (size_t)b * M_SZ;

#pragma unroll 4
    for (int mt = 0; mt < M_SZ / 16; ++mt) {
        h8 bf = yb[mt * 64 + l];          // coalesced 1KB/wave, L2-hit
        float y2v = y2b[mt * 16 + lc];    // 16 values, broadcast across groups

        f4 z = {0.f, 0.f, 0.f, 0.f};
        f4 acc0 = __builtin_amdgcn_mfma_f32_16x16x32_f16(a0, bf, z, 0, 0, 0);
        f4 acc1 = __builtin_amdgcn_mfma_f32_16x16x32_f16(a1, bf, z, 0, 0, 0);

        float cm = INF;
#pragma unroll
        for (int r = 0; r < 4; ++r) {
            float d0 = fmaf(-2.f, acc0[r], x20[r] + y2v);
            float d1 = fmaf(-2.f, acc1[r], x21[r] + y2v);
            rm0[r] = fminf(rm0[r], d0);
            rm1[r] = fminf(rm1[r], d1);
            cm = fminf(cm, fminf(d0, d1));
        }
        // col-min across the wave's 32 rows (groups g and g^1, g^2)
        cm = fminf(cm, __shfl_xor(cm, 16));
        cm = fminf(cm, __shfl_xor(cm, 32));
        if (l < 16)
            atomicMin(&cmb[mt * 16 + l], __float_as_uint(cm));
    }

    // row-min: reduce across the 16 column-lanes
#pragma unroll
    for (int m = 1; m <= 8; m <<= 1) {
#pragma unroll
        for (int r = 0; r < 4; ++r) {
            rm0[r] = fminf(rm0[r], __shfl_xor(rm0[r], m));
            rm1[r] = fminf(rm1[r], __shfl_xor(rm1[r], m));
        }
    }
    if (lc == 0) {
        float* rp = rowmin_g + (size_t)b * N_SZ + row0 + ((l >> 4) << 2);
        *(f4*)rp        = rm0;   // rows row0 + g*4 + r
        *(f4*)(rp + 16) = rm1;   // rows row0 + 16 + g*4 + r
    }
}

// ---------------------------------------------------------------------------
// Finalize: sqrt + deterministic two-stage sum over rowmin ++ colmin.
// ---------------------------------------------------------------------------
__global__ __launch_bounds__(256)
void finalize1(const float* __restrict__ vals, float* __restrict__ partials, int total4) {
    const float4* v4 = reinterpret_cast<const float4*>(vals);
    float s = 0.f;
    for (int i = blockIdx.x * blockDim.x + threadIdx.x; i < total4;
         i += gridDim.x * blockDim.x) {
        float4 v = v4[i];
        s += sqrtf(fmaxf(v.x, 0.f)) + sqrtf(fmaxf(v.y, 0.f)) +
             sqrtf(fmaxf(v.z, 0.f)) + sqrtf(fmaxf(v.w, 0.f));
    }
    __shared__ float wsum[4];
#pragma unroll
    for (int o = 32; o > 0; o >>= 1) s += __shfl_down(s, o, 64);
    if ((threadIdx.x & 63) == 0) wsum[threadIdx.x >> 6] = s;
    __syncthreads();
    if (threadIdx.x == 0)
        partials[blockIdx.x] = wsum[0] + wsum[1] + wsum[2] + wsum[3];
}

__global__ __launch_bounds__(64)
void finalize2(const float* __restrict__ partials, float* __restrict__ out, float scale) {
    float s = partials[threadIdx.x];
#pragma unroll
    for (int o = 32; o > 0; o >>= 1) s += __shfl_down(s, o, 64);
    if (threadIdx.x == 0) out[0] = s * scale;
}

extern "C" void kernel_launch(void* const* d_in, const int* in_sizes, int n_in,
                              void* d_out, int out_size, void* d_ws, size_t ws_size,
                              hipStream_t stream) {
    const float* X = (const float*)d_in[0];
    const float* Y = (const float*)d_in[1];

    float* ws       = (float*)d_ws;
    float* rowmin   = ws;                      // 65536 f
    float* colmin   = rowmin + 65536;          // 65536 f (contiguous with rowmin)
    float* partials = colmin + 65536;          // 64 f
    float* x2       = partials + 64;           // 65536 f
    float* y2       = x2 + 65536;              // 65536 f
    h8*    Xpk      = (h8*)(y2 + 65536);       // 262144 h8 (4.2 MB)
    h8*    Ypk      = Xpk + 262144;            // 262144 h8 (4.2 MB)

    dim3 pgrid(1024, 2);
    pack_kernel<<<pgrid, 256, 0, stream>>>(X, Y, Xpk, Ypk, x2, y2);

    // colmin init to huge float (0x7F7F7F7F ~ 3.39e38)
    hipMemsetAsync(colmin, 0x7F, 65536 * sizeof(float), stream);

    dim3 grid(N_SZ / 128, B_SZ);
    chamfer_mfma<<<grid, 256, 0, stream>>>(Xpk, Ypk, x2, y2, rowmin,
                                           (unsigned int*)colmin);

    finalize1<<<64, 256, 0, stream>>>(rowmin, partials, (2 * 65536) / 4);
    finalize2<<<1, 64, 0, stream>>>(partials, (float*)d_out, 1.0f / 131072.0f);
}

// Round 3
// 47.580 us; speedup vs baseline: 2.8679x; 1.8056x over previous
//
#include <hip/hip_runtime.h>
#include <math.h>

// Problem shape (fixed by harness reference)
#define B_SZ 32
#define NM   2048     // N == M == 2048
#define D_SZ 32

typedef __attribute__((ext_vector_type(8))) _Float16 h8;   // MFMA A/B frag: 8 f16 = 4 VGPRs
typedef __attribute__((ext_vector_type(4))) float f4;      // MFMA C/D frag

// ---------------------------------------------------------------------------
// Pack X (and Y) into MFMA-fragment-ready f16 layout + fused squared norms
// (verified correct in round 2: absmax 0.0). Tile t = 16 consecutive rows of
// flattened [B*NM]; lane l holds row t*16+(l&15), k = {4g+j} U {16+4g+j}.
// ---------------------------------------------------------------------------
__global__ __launch_bounds__(256)
void pack_kernel(const float* __restrict__ srcX, const float* __restrict__ srcY,
                 h8* __restrict__ dstX, h8* __restrict__ dstY,
                 float* __restrict__ nrmX, float* __restrict__ nrmY)
{
    const int gid = blockIdx.x * 256 + threadIdx.x;   // one thread per (tile,lane)
    const float* src = blockIdx.y ? srcY : srcX;
    h8*          dst = blockIdx.y ? dstY : dstX;
    float*       nrm = blockIdx.y ? nrmY : nrmX;

    const int l   = gid & 63;
    const int t   = gid >> 6;
    const int row = t * 16 + (l & 15);
    const int k0  = (l >> 4) * 4;

    const float* p = src + (size_t)row * D_SZ;
    f4 v0 = *(const f4*)(p + k0);        // k = k0..k0+3
    f4 v1 = *(const f4*)(p + 16 + k0);   // k = 16+k0..16+k0+3

    h8 h;
    h[0] = (_Float16)v0[0]; h[1] = (_Float16)v0[1];
    h[2] = (_Float16)v0[2]; h[3] = (_Float16)v0[3];
    h[4] = (_Float16)v1[0]; h[5] = (_Float16)v1[1];
    h[6] = (_Float16)v1[2]; h[7] = (_Float16)v1[3];
    dst[gid] = h;

    float s = 0.f;
#pragma unroll
    for (int j = 0; j < 4; ++j) {
        s = fmaf(v0[j], v0[j], s);
        s = fmaf(v1[j], v1[j], s);
    }
    s += __shfl_xor(s, 16);
    s += __shfl_xor(s, 32);
    if (l < 16) nrm[row] = s;   // exact fp32 norms
}

// ---------------------------------------------------------------------------
// One directional pass. dir=0: rows=X, cols=Y (X_inf). dir=1: roles swapped.
// Block = 4 waves; wave owns 64 rows (4 A-frags in registers). B-tiles staged
// 4-at-a-time in double-buffered LDS (wave w stages tile w of the group; one
// barrier per group). MFMA C-operand seeded with -0.5*qnorm[col] so the
// epilogue is a single fmaxf per element:
//     min_j d2[i,j] = pnorm[i] - 2 * max_j (dot[i,j] - 0.5*qnorm[j])
// Output: mp[(dir*nh + half)][b][row] = max-proxy (finalize applies norms).
// C/D layout (m89-verified): col = lane&15, row = (lane>>4)*4 + reg.
// ---------------------------------------------------------------------------
__global__ __launch_bounds__(256)
void chamfer_pass(const h8* __restrict__ Xpk, const h8* __restrict__ Ypk,
                  const float* __restrict__ x2g, const float* __restrict__ y2g,
                  float* __restrict__ mp, int nh, int tph /* = 128/nh */)
{
    __shared__ h8 buf[2][256];   // 2 x (4 tiles x 64 frags) = 8 KB

    const int tid = threadIdx.x;
    const int w   = tid >> 6;
    const int l   = tid & 63;
    const int lc  = l & 15;
    const int b   = blockIdx.y;
    const int dir = blockIdx.z / nh;
    const int half = blockIdx.z % nh;

    const h8* Ppk = dir ? Ypk : Xpk;
    const h8* Qpk = dir ? Xpk : Ypk;
    const float* qn = dir ? x2g : y2g;

    const int row0 = blockIdx.x * 256 + w * 64;           // within batch
    const size_t pt0 = ((size_t)b * NM + row0) >> 4;      // global 16-row tile
    const h8* pa = Ppk + pt0 * 64 + l;
    h8 a0 = pa[0], a1 = pa[64], a2 = pa[128], a3 = pa[192];

    const int mt0 = half * tph;
    const h8* qb = Qpk + ((size_t)b * (NM / 16) + mt0) * 64;
    const float* qnb = qn + (size_t)b * NM + mt0 * 16;

    const float NEGINF = -3.0e38f;
    f4 mx0 = {NEGINF, NEGINF, NEGINF, NEGINF};
    f4 mx1 = mx0, mx2 = mx0, mx3 = mx0;

    const int ngroups = tph >> 2;

    // prologue: stage group 0 (wave w stages tile w)
    h8 pf = qb[(size_t)w * 64 + l];
    buf[0][w * 64 + l] = pf;
    __syncthreads();

    for (int g = 0; g < ngroups; ++g) {
        if (g + 1 < ngroups)                      // issue next group's load early
            pf = qb[(size_t)((g + 1) * 4 + w) * 64 + l];
        const int cur = g & 1;
#pragma unroll
        for (int t = 0; t < 4; ++t) {
            h8 bf = buf[cur][t * 64 + l];
            float c = -0.5f * qnb[(g * 4 + t) * 16 + lc];
            f4 cs = {c, c, c, c};
            f4 q0 = __builtin_amdgcn_mfma_f32_16x16x32_f16(a0, bf, cs, 0, 0, 0);
            f4 q1 = __builtin_amdgcn_mfma_f32_16x16x32_f16(a1, bf, cs, 0, 0, 0);
            f4 q2 = __builtin_amdgcn_mfma_f32_16x16x32_f16(a2, bf, cs, 0, 0, 0);
            f4 q3 = __builtin_amdgcn_mfma_f32_16x16x32_f16(a3, bf, cs, 0, 0, 0);
#pragma unroll
            for (int r = 0; r < 4; ++r) {
                mx0[r] = fmaxf(mx0[r], q0[r]);
                mx1[r] = fmaxf(mx1[r], q1[r]);
                mx2[r] = fmaxf(mx2[r], q2[r]);
                mx3[r] = fmaxf(mx3[r], q3[r]);
            }
        }
        if (g + 1 < ngroups) {
            buf[cur ^ 1][w * 64 + l] = pf;        // write-late (T14)
            __syncthreads();                      // one barrier per group
        }
    }

    // reduce max across the 16 column-lanes
#pragma unroll
    for (int m = 1; m <= 8; m <<= 1) {
#pragma unroll
        for (int r = 0; r < 4; ++r) {
            mx0[r] = fmaxf(mx0[r], __shfl_xor(mx0[r], m));
            mx1[r] = fmaxf(mx1[r], __shfl_xor(mx1[r], m));
            mx2[r] = fmaxf(mx2[r], __shfl_xor(mx2[r], m));
            mx3[r] = fmaxf(mx3[r], __shfl_xor(mx3[r], m));
        }
    }
    if (lc == 0) {   // 4 lanes (g = l>>4) store rows row0 + k*16 + g*4 .. +3
        float* out = mp + ((size_t)(dir * nh + half) * B_SZ + b) * NM
                        + row0 + ((l >> 4) << 2);
        *(f4*)(out)      = mx0;
        *(f4*)(out + 16) = mx1;
        *(f4*)(out + 32) = mx2;
        *(f4*)(out + 48) = mx3;
    }
}

// ---------------------------------------------------------------------------
// Finalize: d2 = nrm - 2*max(halves), clamp, sqrt, deterministic tree sum.
// Exactly 32768 f4 elements -> grid 128 x 256, one f4 per thread.
// ---------------------------------------------------------------------------
__global__ __launch_bounds__(256)
void finalize1(const float* __restrict__ mp, const float* __restrict__ nrm,
               float* __restrict__ partials, int nh)
{
    const int i   = blockIdx.x * 256 + threadIdx.x;   // f4 index in [0, 32768)
    const int dir = i >> 14;
    const int r4  = i & 16383;
    const f4* n4 = (const f4*)(nrm + dir * 65536);
    const f4* m0 = (const f4*)(mp + (size_t)dir * nh * 65536);
    const f4* m1 = (const f4*)(mp + ((size_t)dir * nh + (nh - 1)) * 65536);
    f4 nv = n4[r4];
    f4 pa = m0[r4];
    f4 pb = m1[r4];   // nh==1: same as pa
    float s = 0.f;
#pragma unroll
    for (int r = 0; r < 4; ++r) {
        float d2 = fmaf(-2.f, fmaxf(pa[r], pb[r]), nv[r]);
        s += sqrtf(fmaxf(d2, 0.f));
    }
    __shared__ float wsum[4];
#pragma unroll
    for (int o = 32; o > 0; o >>= 1) s += __shfl_down(s, o, 64);
    if ((threadIdx.x & 63) == 0) wsum[threadIdx.x >> 6] = s;
    __syncthreads();
    if (threadIdx.x == 0)
        partials[blockIdx.x] = wsum[0] + wsum[1] + wsum[2] + wsum[3];
}

__global__ __launch_bounds__(64)
void finalize2(const float* __restrict__ partials, float* __restrict__ out, float scale)
{
    float s = partials[threadIdx.x] + partials[threadIdx.x + 64];
#pragma unroll
    for (int o = 32; o > 0; o >>= 1) s += __shfl_down(s, o, 64);
    if (threadIdx.x == 0) out[0] = s * scale;
}

extern "C" void kernel_launch(void* const* d_in, const int* in_sizes, int n_in,
                              void* d_out, int out_size, void* d_ws, size_t ws_size,
                              hipStream_t stream) {
    const float* X = (const float*)d_in[0];
    const float* Y = (const float*)d_in[1];

    // ws needed: mp nh*131072 f + partials 128 f + nrm 131072 f + packed 8.39 MB
    // nh=2 -> ~9.97 MB, nh=1 -> ~9.44 MB (round-2 proven). Pick nh by ws_size.
    const int nh  = (ws_size >= 10100000u) ? 2 : 1;
    const int tph = 128 / nh;

    float* ws       = (float*)d_ws;
    float* mp       = ws;                              // nh*2*32*2048 floats
    float* partials = mp + (size_t)nh * 131072;        // 128 floats
    float* nrm      = partials + 128;                  // 131072 floats (x2 then y2)
    h8*    Xpk      = (h8*)(nrm + 131072);             // 262144 h8 (4.19 MB)
    h8*    Ypk      = Xpk + 262144;                    // 262144 h8 (4.19 MB)

    dim3 pgrid(1024, 2);
    pack_kernel<<<pgrid, 256, 0, stream>>>(X, Y, Xpk, Ypk, nrm, nrm + 65536);

    dim3 grid(NM / 256, B_SZ, 2 * nh);
    chamfer_pass<<<grid, 256, 0, stream>>>(Xpk, Ypk, nrm, nrm + 65536,
                                           mp, nh, tph);

    finalize1<<<128, 256, 0, stream>>>(mp, nrm, partials, nh);
    finalize2<<<1, 64, 0, stream>>>(partials, (float*)d_out, 1.0f / 131072.0f);
}